// Round 1
// baseline (1421.021 us; speedup 1.0000x reference)
//
#include <hip/hip_runtime.h>
#include <math.h>

typedef __bf16 bf16;
typedef __bf16 bf16x8 __attribute__((ext_vector_type(8)));
typedef float f32x4 __attribute__((ext_vector_type(4)));

#define T_TOK 4096
#define D_DIM 1024
#define E_EXP 8
#define F_DIM 4096
#define BM 128
#define BN 128
#define BK 64
#define PAD_SLOTS 9216   // sum_e ceil(cnt_e/128)*128 <= 8192 + 8*127 = 9208

// ---------------- router: f32 scores, exact top-2, softmax over top-2 ----------------
__global__ __launch_bounds__(64) void router_kernel(
    const float* __restrict__ x, const float* __restrict__ gw,
    int* __restrict__ eidx, float* __restrict__ pval, int* __restrict__ cnt)
{
  const int t = blockIdx.x;
  const int lane = threadIdx.x;
  const float* xr = x + (size_t)t * D_DIM;
  float s[E_EXP];
#pragma unroll
  for (int e = 0; e < E_EXP; ++e) s[e] = 0.f;
#pragma unroll
  for (int j = 0; j < D_DIM / 64; ++j) {
    const int d = lane * (D_DIM / 64) + j;
    const float xv = xr[d];
    const float* g = gw + (size_t)d * E_EXP;
#pragma unroll
    for (int e = 0; e < E_EXP; ++e) s[e] += xv * g[e];
  }
#pragma unroll
  for (int off = 32; off > 0; off >>= 1) {
#pragma unroll
    for (int e = 0; e < E_EXP; ++e) s[e] += __shfl_xor(s[e], off, 64);
  }
  if (lane == 0) {
    int i0 = 0;
#pragma unroll
    for (int e = 1; e < E_EXP; ++e) if (s[e] > s[i0]) i0 = e;
    int i1 = (i0 == 0) ? 1 : 0;
#pragma unroll
    for (int e = 0; e < E_EXP; ++e) if (e != i0 && s[e] > s[i1]) i1 = e;
    const float p1 = 1.f / (1.f + expf(s[i0] - s[i1]));  // s[i0] >= s[i1]
    eidx[2 * t] = i0;  eidx[2 * t + 1] = i1;
    pval[2 * t] = 1.f - p1;  pval[2 * t + 1] = p1;
    atomicAdd(&cnt[i0], 1);
    atomicAdd(&cnt[i1], 1);
  }
}

// ---------------- prefix: 128-aligned expert segment offsets ----------------
__global__ void prefix_kernel(const int* __restrict__ cnt, int* __restrict__ off,
                              int* __restrict__ cursor)
{
  if (blockIdx.x == 0 && threadIdx.x == 0) {
    int acc = 0;
    for (int e = 0; e < E_EXP; ++e) {
      off[e] = acc;
      cursor[e] = acc;
      acc += ((cnt[e] + BM - 1) / BM) * BM;
    }
    off[E_EXP] = acc;
  }
}

// ---------------- scatter tokens into flat padded slot list ----------------
__global__ __launch_bounds__(256) void scatter_kernel(
    const int* __restrict__ eidx, const float* __restrict__ pval,
    int* __restrict__ cursor, int* __restrict__ tok_flat, float* __restrict__ prob_flat)
{
  const int i = blockIdx.x * 256 + threadIdx.x;
  if (i < T_TOK * 2) {
    const int e = eidx[i];
    const int pos = atomicAdd(&cursor[e], 1);
    tok_flat[pos] = i >> 1;
    prob_flat[pos] = pval[i];
  }
}

// ---------------- cast x to bf16 ----------------
__global__ __launch_bounds__(256) void xcast_kernel(const float* __restrict__ x,
                                                    bf16* __restrict__ xb)
{
  const size_t i = (size_t)(blockIdx.x * 256 + threadIdx.x) * 8;
  const float4 a = *(const float4*)(x + i);
  const float4 b = *(const float4*)(x + i + 4);
  union { bf16 v[8]; int4 q; } u;
  u.v[0] = (bf16)a.x; u.v[1] = (bf16)a.y; u.v[2] = (bf16)a.z; u.v[3] = (bf16)a.w;
  u.v[4] = (bf16)b.x; u.v[5] = (bf16)b.y; u.v[6] = (bf16)b.z; u.v[7] = (bf16)b.w;
  *(int4*)(xb + i) = u.q;
}

// ---------------- grouped GEMM ----------------
// MODE 0: A = gathered xb rows [*,1024] bf16, B = w1[e] (f32 [1024][4096]),
//         epilogue: h = gelu(A*B + b1) -> bf16
// MODE 1: A = h rows [*,4096] bf16, B = w2[e] (f32 [4096][1024]),
//         epilogue: atomicAdd(out[tok], prob*(A*B + b2))
template <int MODE>
__global__ __launch_bounds__(256) void gemm_kernel(
    const bf16* __restrict__ Abase, const float* __restrict__ Bsrc,
    const float* __restrict__ bias, const int* __restrict__ cnt,
    const int* __restrict__ off, const int* __restrict__ tok_flat,
    const float* __restrict__ prob_flat, bf16* __restrict__ Hout,
    float* __restrict__ Out)
{
  constexpr int K = (MODE == 0) ? 1024 : 4096;
  constexpr int N = (MODE == 0) ? 4096 : 1024;
  constexpr int NT = N / BN;

  const int b = blockIdx.x;
  const int nt = b % NT;
  const int mt = (b / NT) % 32;
  const int e  = b / (NT * 32);
  const int c = cnt[e];
  if (mt * BM >= c) return;
  const int rowBase = off[e] + mt * BM;
  const int nBase = nt * BN;

  __shared__ char smem[32 * 1024];  // sA [128][64]bf16 @0 ; sB(T) [128][64]bf16 @16384

  const int tid = threadIdx.x;
  const int lane = tid & 63;
  const int wid = tid >> 6;
  const int mW = (wid >> 1) * 64;
  const int nW = (wid & 1) * 64;

  // A staging: thread covers rows rl = p*64 + tid>>2, k-quarter aq
  const int aq = tid & 3;
  const bf16* arow[2];
#pragma unroll
  for (int p = 0; p < 2; ++p) {
    const int row = rowBase + p * 64 + (tid >> 2);
    if (MODE == 0) {
      int tok = tok_flat[row];
      if (tok < 0) tok = 0;          // pad row: compute garbage, never scattered
      arow[p] = Abase + (size_t)tok * K;
    } else {
      arow[p] = Abase + (size_t)row * K;
    }
  }

  // B staging: thread loads 8 k-rows x 4 cols (float4), transposes to [n][k] bf16
  const int bn0 = (tid & 31) * 4;
  const int bkq = tid >> 5;  // 0..7
  const float* bp0 = Bsrc + (size_t)e * K * N + (size_t)(bkq * 8) * N + nBase + bn0;

  f32x4 acc[4][4];
#pragma unroll
  for (int m = 0; m < 4; ++m)
#pragma unroll
    for (int n = 0; n < 4; ++n) acc[m][n] = (f32x4){0.f, 0.f, 0.f, 0.f};

  for (int kt = 0; kt < K / BK; ++kt) {
    // ---- stage A (bf16 copy, XOR-swizzled rows) ----
#pragma unroll
    for (int p = 0; p < 2; ++p) {
      const int rl = p * 64 + (tid >> 2);
      const int4* src = (const int4*)(arow[p] + kt * BK + aq * 16);
      const int4 v0 = src[0];
      const int4 v1 = src[1];
      const int base = rl * 128 + aq * 32;
      const int sw = (rl & 7) << 4;
      *(int4*)(smem + ((base) ^ sw)) = v0;
      *(int4*)(smem + ((base + 16) ^ sw)) = v1;
    }
    // ---- stage B (f32 load, cvt bf16, transpose to [n][k]) ----
    {
      const float* bp = bp0 + (size_t)kt * BK * N;
      float4 bv[8];
#pragma unroll
      for (int kk = 0; kk < 8; ++kk) bv[kk] = *(const float4*)(bp + (size_t)kk * N);
#pragma unroll
      for (int ci = 0; ci < 4; ++ci) {
        const int cc = (ci + tid) & 3;  // rotate write order to spread banks
        union { bf16 v[8]; int4 q; } u;
#pragma unroll
        for (int kk = 0; kk < 8; ++kk) u.v[kk] = (bf16)(((const float*)&bv[kk])[cc]);
        const int n = bn0 + cc;
        const int base = 16384 + n * 128 + bkq * 16;
        *(int4*)(smem + (base ^ ((n & 7) << 4))) = u.q;
      }
    }
    __syncthreads();
    // ---- MFMA ----
#pragma unroll
    for (int ks = 0; ks < 2; ++ks) {
      const int kb = ks * 64 + ((lane >> 4) << 4);  // byte offset of k within row
      bf16x8 af[4], bfr[4];
#pragma unroll
      for (int m = 0; m < 4; ++m) {
        const int row = mW + m * 16 + (lane & 15);
        af[m] = *(const bf16x8*)(smem + ((row * 128 + kb) ^ ((row & 7) << 4)));
      }
#pragma unroll
      for (int n = 0; n < 4; ++n) {
        const int row = nW + n * 16 + (lane & 15);
        bfr[n] = *(const bf16x8*)(smem + (16384 + ((row * 128 + kb) ^ ((row & 7) << 4))));
      }
#pragma unroll
      for (int m = 0; m < 4; ++m)
#pragma unroll
        for (int n = 0; n < 4; ++n)
          acc[m][n] = __builtin_amdgcn_mfma_f32_16x16x32_bf16(af[m], bfr[n], acc[m][n], 0, 0, 0);
    }
    __syncthreads();
  }

  // ---- epilogue ----
  const int col0 = nW + (lane & 15);
  const int rsub = (lane >> 4) * 4;
  if (MODE == 0) {
#pragma unroll
    for (int m = 0; m < 4; ++m) {
#pragma unroll
      for (int n = 0; n < 4; ++n) {
        const int colg = nBase + col0 + n * 16;
        const float bb = bias[e * N + colg];
#pragma unroll
        for (int r = 0; r < 4; ++r) {
          const int rowl = mW + m * 16 + rsub + r;
          float v = acc[m][n][r] + bb;
          v = 0.5f * v * (1.0f + erff(v * 0.70710678118f));
          Hout[(size_t)(rowBase + rowl) * F_DIM + colg] = (bf16)v;
        }
      }
    }
  } else {
#pragma unroll
    for (int m = 0; m < 4; ++m) {
#pragma unroll
      for (int r = 0; r < 4; ++r) {
        const int slot = rowBase + mW + m * 16 + rsub + r;
        const int tok = tok_flat[slot];
        if (tok < 0) continue;
        const float p = prob_flat[slot];
#pragma unroll
        for (int n = 0; n < 4; ++n) {
          const int colg = nBase + col0 + n * 16;
          const float v = (acc[m][n][r] + bias[e * N + colg]) * p;
          atomicAdd(Out + (size_t)tok * D_DIM + colg, v);
        }
      }
    }
  }
}

extern "C" void kernel_launch(void* const* d_in, const int* in_sizes, int n_in,
                              void* d_out, int out_size, void* d_ws, size_t ws_size,
                              hipStream_t stream) {
  const float* x      = (const float*)d_in[0];
  const float* gate_w = (const float*)d_in[1];
  const float* w1     = (const float*)d_in[2];
  const float* b1     = (const float*)d_in[3];
  const float* w2     = (const float*)d_in[4];
  const float* b2     = (const float*)d_in[5];
  float* out = (float*)d_out;

  char* ws = (char*)d_ws;
  size_t o = 0;
  bf16* xb = (bf16*)(ws + o);        o += (size_t)T_TOK * D_DIM * 2;       // 8 MiB
  bf16* h  = (bf16*)(ws + o);        o += (size_t)PAD_SLOTS * F_DIM * 2;   // 72 MiB
  int*   tok_flat  = (int*)(ws + o);   o += PAD_SLOTS * 4;
  float* prob_flat = (float*)(ws + o); o += PAD_SLOTS * 4;
  int*   eidx      = (int*)(ws + o);   o += T_TOK * 2 * 4;
  float* pval      = (float*)(ws + o); o += T_TOK * 2 * 4;
  int*   cnt       = (int*)(ws + o);   o += 32;
  int*   cursor    = (int*)(ws + o);   o += 32;
  int*   off       = (int*)(ws + o);   o += 64;

  hipMemsetAsync(cnt, 0, 32, stream);
  hipMemsetAsync(tok_flat, 0xFF, PAD_SLOTS * 4, stream);  // -1 = pad slot
  hipMemsetAsync(out, 0, (size_t)out_size * 4, stream);

  router_kernel<<<T_TOK, 64, 0, stream>>>(x, gate_w, eidx, pval, cnt);
  prefix_kernel<<<1, 64, 0, stream>>>(cnt, off, cursor);
  scatter_kernel<<<(T_TOK * 2) / 256, 256, 0, stream>>>(eidx, pval, cursor, tok_flat, prob_flat);
  xcast_kernel<<<(T_TOK * D_DIM) / (256 * 8), 256, 0, stream>>>(x, xb);

  gemm_kernel<0><<<E_EXP * 32 * (F_DIM / BN), 256, 0, stream>>>(
      xb, w1, b1, cnt, off, tok_flat, prob_flat, h, nullptr);
  gemm_kernel<1><<<E_EXP * 32 * (D_DIM / BN), 256, 0, stream>>>(
      h, w2, b2, cnt, off, tok_flat, prob_flat, nullptr, out);
}

// Round 3
// 790.850 us; speedup vs baseline: 1.7968x; 1.7968x over previous
//
#include <hip/hip_runtime.h>
#include <math.h>

typedef __bf16 bf16;
typedef __bf16 bf16x8 __attribute__((ext_vector_type(8)));
typedef float f32x4 __attribute__((ext_vector_type(4)));

#define T_TOK 4096
#define D_DIM 1024
#define E_EXP 8
#define F_DIM 4096
#define BM 128
#define BN 128
#define BK 64
#define PAD_SLOTS 9216

__device__ __forceinline__ void gload16(const bf16* g, bf16* l) {
  __builtin_amdgcn_global_load_lds(
      (const __attribute__((address_space(1))) void*)g,
      (__attribute__((address_space(3))) void*)l, 16, 0, 0);
}

// ---------------- router: f32 scores, exact top-2, softmax over top-2 ----------------
__global__ __launch_bounds__(64) void router_kernel(
    const float* __restrict__ x, const float* __restrict__ gw,
    int* __restrict__ eidx, float* __restrict__ pval, int* __restrict__ cnt)
{
  const int t = blockIdx.x;
  const int lane = threadIdx.x;
  const float* xr = x + (size_t)t * D_DIM;
  float s[E_EXP];
#pragma unroll
  for (int e = 0; e < E_EXP; ++e) s[e] = 0.f;
#pragma unroll
  for (int j = 0; j < D_DIM / 64; ++j) {
    const int d = lane * (D_DIM / 64) + j;
    const float xv = xr[d];
    const float* g = gw + (size_t)d * E_EXP;
#pragma unroll
    for (int e = 0; e < E_EXP; ++e) s[e] += xv * g[e];
  }
#pragma unroll
  for (int off = 32; off > 0; off >>= 1) {
#pragma unroll
    for (int e = 0; e < E_EXP; ++e) s[e] += __shfl_xor(s[e], off, 64);
  }
  if (lane == 0) {
    int i0 = 0;
#pragma unroll
    for (int e = 1; e < E_EXP; ++e) if (s[e] > s[i0]) i0 = e;
    int i1 = (i0 == 0) ? 1 : 0;
#pragma unroll
    for (int e = 0; e < E_EXP; ++e) if (e != i0 && s[e] > s[i1]) i1 = e;
    const float p1 = 1.f / (1.f + expf(s[i0] - s[i1]));
    eidx[2 * t] = i0;  eidx[2 * t + 1] = i1;
    pval[2 * t] = 1.f - p1;  pval[2 * t + 1] = p1;
    atomicAdd(&cnt[i0], 1);
    atomicAdd(&cnt[i1], 1);
  }
}

__global__ void prefix_kernel(const int* __restrict__ cnt, int* __restrict__ off,
                              int* __restrict__ cursor)
{
  if (blockIdx.x == 0 && threadIdx.x == 0) {
    int acc = 0;
    for (int e = 0; e < E_EXP; ++e) {
      off[e] = acc;
      cursor[e] = acc;
      acc += ((cnt[e] + BM - 1) / BM) * BM;
    }
    off[E_EXP] = acc;
  }
}

__global__ __launch_bounds__(256) void scatter_kernel(
    const int* __restrict__ eidx, const float* __restrict__ pval,
    int* __restrict__ cursor, int* __restrict__ tok_flat,
    float* __restrict__ prob_flat, int* __restrict__ slot_of)
{
  const int i = blockIdx.x * 256 + threadIdx.x;
  if (i < T_TOK * 2) {
    const int e = eidx[i];
    const int pos = atomicAdd(&cursor[e], 1);
    tok_flat[pos] = i >> 1;
    prob_flat[pos] = pval[i];
    slot_of[i] = pos;
  }
}

__global__ __launch_bounds__(256) void xcast_kernel(const float* __restrict__ x,
                                                    bf16* __restrict__ xb)
{
  const size_t i = (size_t)(blockIdx.x * 256 + threadIdx.x) * 8;
  const float4 a = *(const float4*)(x + i);
  const float4 b = *(const float4*)(x + i + 4);
  union { bf16 v[8]; int4 q; } u;
  u.v[0] = (bf16)a.x; u.v[1] = (bf16)a.y; u.v[2] = (bf16)a.z; u.v[3] = (bf16)a.w;
  u.v[4] = (bf16)b.x; u.v[5] = (bf16)b.y; u.v[6] = (bf16)b.z; u.v[7] = (bf16)b.w;
  *(int4*)(xb + i) = u.q;
}

// ---------------- weight transpose+convert: src [E][R][C] f32 -> dst [E][C][R] bf16 ----------------
__global__ __launch_bounds__(256) void wtrans_kernel(const float* __restrict__ src,
                                                     bf16* __restrict__ dst,
                                                     int R, int C)
{
  __shared__ float tile[64][68];
  const int e = blockIdx.z;
  const int r0 = blockIdx.y * 64;
  const int c0 = blockIdx.x * 64;
  const float* sp = src + (size_t)e * R * C;
  const int tr = threadIdx.x >> 4;          // 0..15
  const int tc = (threadIdx.x & 15) * 4;    // 0..60
#pragma unroll
  for (int p = 0; p < 4; ++p) {
    const int r = p * 16 + tr;
    const float4 v = *(const float4*)(sp + (size_t)(r0 + r) * C + c0 + tc);
    *(float4*)&tile[r][tc] = v;
  }
  __syncthreads();
  bf16* dp = dst + (size_t)e * C * R;
  const int oc = threadIdx.x & 31;          // col within tile
  const int orr = (threadIdx.x >> 5) * 8;   // 0..56
#pragma unroll
  for (int p = 0; p < 2; ++p) {
    const int c = p * 32 + oc;
    union { bf16 v[8]; int4 q; } u;
#pragma unroll
    for (int j = 0; j < 8; ++j) u.v[j] = (bf16)tile[orr + j][c];
    *(int4*)(dp + (size_t)(c0 + c) * R + r0 + orr) = u.q;
  }
}

// ---------------- grouped GEMM, m97 structure ----------------
// MODE 0: A = gathered xb rows [*,1024], B = w1T [E][4096][1024], epi: h=gelu(.+b1) bf16
// MODE 1: A = h rows [*,4096],   B = w2T [E][1024][4096], epi: y[slot]=p*(.+b2) bf16
template <int MODE>
__global__ __launch_bounds__(256) void gemm_kernel(
    const bf16* __restrict__ Abase, const bf16* __restrict__ BT,
    const float* __restrict__ bias, const int* __restrict__ cnt,
    const int* __restrict__ off, const int* __restrict__ tok_flat,
    const float* __restrict__ prob_flat, bf16* __restrict__ Hout,
    bf16* __restrict__ Yout)
{
  constexpr int K = (MODE == 0) ? 1024 : 4096;
  constexpr int N = (MODE == 0) ? 4096 : 1024;
  constexpr int NT = N / BN;

  const int b = blockIdx.x;
  const int nt = b % NT;
  const int mt = (b / NT) % 32;
  const int e  = b / (NT * 32);
  if (mt * BM >= cnt[e]) return;
  const int rowBase = off[e] + mt * BM;
  const int nBase = nt * BN;

  __shared__ bf16 sA[BM * BK];
  __shared__ bf16 sB[BN * BK];

  const int tid = threadIdx.x;
  const int lane = tid & 63;
  const int wid = tid >> 6;
  const int mW = (wid >> 1) * 64;
  const int nW = (wid & 1) * 64;

  // staging: wave w covers LDS rows [w*32, w*32+32); issue j covers 8 rows;
  // lane covers row j*8 + (lane>>3), 16B chunk (lane&7)
  const bf16* aptr[4];
  const bf16* bptr[4];
#pragma unroll
  for (int j = 0; j < 4; ++j) {
    const int r = wid * 32 + j * 8 + (lane >> 3);
    if (MODE == 0) {
      int tok = tok_flat[rowBase + r];
      if (tok < 0) tok = 0;
      aptr[j] = Abase + (size_t)tok * K + (lane & 7) * 8;
    } else {
      aptr[j] = Abase + (size_t)(rowBase + r) * K + (lane & 7) * 8;
    }
    bptr[j] = BT + ((size_t)e * N + nBase + r) * K + (lane & 7) * 8;
  }

  f32x4 acc[4][4];
#pragma unroll
  for (int m = 0; m < 4; ++m)
#pragma unroll
    for (int n = 0; n < 4; ++n) acc[m][n] = (f32x4){0.f, 0.f, 0.f, 0.f};

  for (int kt = 0; kt < K / BK; ++kt) {
#pragma unroll
    for (int j = 0; j < 4; ++j) {
      gload16(aptr[j] + kt * BK, &sA[(wid * 32 + j * 8) * BK]);
      gload16(bptr[j] + kt * BK, &sB[(wid * 32 + j * 8) * BK]);
    }
    __syncthreads();   // compiler drains vmcnt(0) here
#pragma unroll
    for (int ks = 0; ks < 2; ++ks) {
      const int kb = ks * 64 + ((lane >> 4) << 4);  // byte offset within 128B row
      bf16x8 af[4], bfr[4];
#pragma unroll
      for (int m = 0; m < 4; ++m) {
        const int row = mW + m * 16 + (lane & 15);
        af[m] = *(const bf16x8*)((const char*)sA + row * 128 + kb);
      }
#pragma unroll
      for (int n = 0; n < 4; ++n) {
        const int row = nW + n * 16 + (lane & 15);
        bfr[n] = *(const bf16x8*)((const char*)sB + row * 128 + kb);
      }
#pragma unroll
      for (int m = 0; m < 4; ++m)
#pragma unroll
        for (int n = 0; n < 4; ++n)
          acc[m][n] = __builtin_amdgcn_mfma_f32_16x16x32_bf16(af[m], bfr[n], acc[m][n], 0, 0, 0);
    }
    __syncthreads();
  }

  // ---- epilogue ----
  const int col0 = nW + (lane & 15);
  const int rsub = (lane >> 4) * 4;
  if (MODE == 0) {
#pragma unroll
    for (int m = 0; m < 4; ++m) {
#pragma unroll
      for (int n = 0; n < 4; ++n) {
        const int colg = nBase + col0 + n * 16;
        const float bb = bias[e * N + colg];
#pragma unroll
        for (int r = 0; r < 4; ++r) {
          const int rowl = mW + m * 16 + rsub + r;
          float v = acc[m][n][r] + bb;
          v = 0.5f * v * (1.0f + erff(v * 0.70710678118f));
          Hout[(size_t)(rowBase + rowl) * F_DIM + colg] = (bf16)v;
        }
      }
    }
  } else {
#pragma unroll
    for (int m = 0; m < 4; ++m) {
#pragma unroll
      for (int r = 0; r < 4; ++r) {
        const int slot = rowBase + mW + m * 16 + rsub + r;
        const float p = prob_flat[slot];
#pragma unroll
        for (int n = 0; n < 4; ++n) {
          const int colg = nBase + col0 + n * 16;
          const float v = (acc[m][n][r] + bias[e * N + colg]) * p;
          Yout[(size_t)slot * D_DIM + colg] = (bf16)v;
        }
      }
    }
  }
}

// ---------------- combine: out[t] = y[slot0] + y[slot1] ----------------
__global__ __launch_bounds__(256) void combine_kernel(
    const bf16* __restrict__ y, const int* __restrict__ slot_of,
    float* __restrict__ out)
{
  const int i = blockIdx.x * 256 + threadIdx.x;
  const int t = i >> 7;               // 128 threads per token
  const int dq = (i & 127) * 8;
  const int s0 = slot_of[2 * t];
  const int s1 = slot_of[2 * t + 1];
  const bf16x8 a = *(const bf16x8*)(y + (size_t)s0 * D_DIM + dq);
  const bf16x8 b = *(const bf16x8*)(y + (size_t)s1 * D_DIM + dq);
  float4 o0, o1;
  o0.x = (float)a[0] + (float)b[0];  o0.y = (float)a[1] + (float)b[1];
  o0.z = (float)a[2] + (float)b[2];  o0.w = (float)a[3] + (float)b[3];
  o1.x = (float)a[4] + (float)b[4];  o1.y = (float)a[5] + (float)b[5];
  o1.z = (float)a[6] + (float)b[6];  o1.w = (float)a[7] + (float)b[7];
  *(float4*)(out + (size_t)t * D_DIM + dq) = o0;
  *(float4*)(out + (size_t)t * D_DIM + dq + 4) = o1;
}

extern "C" void kernel_launch(void* const* d_in, const int* in_sizes, int n_in,
                              void* d_out, int out_size, void* d_ws, size_t ws_size,
                              hipStream_t stream) {
  const float* x      = (const float*)d_in[0];
  const float* gate_w = (const float*)d_in[1];
  const float* w1     = (const float*)d_in[2];
  const float* b1     = (const float*)d_in[3];
  const float* w2     = (const float*)d_in[4];
  const float* b2     = (const float*)d_in[5];
  float* out = (float*)d_out;

  char* ws = (char*)d_ws;
  size_t o = 0;
  bf16* xb  = (bf16*)(ws + o); o += (size_t)T_TOK * D_DIM * 2;        // 8 MiB
  bf16* h   = (bf16*)(ws + o); o += (size_t)PAD_SLOTS * F_DIM * 2;    // 72 MiB
  bf16* wT  = (bf16*)(ws + o); o += (size_t)E_EXP * D_DIM * F_DIM * 2;// 64 MiB (w1T then w2T)
  bf16* y   = (bf16*)(ws + o); o += (size_t)PAD_SLOTS * D_DIM * 2;    // 18 MiB
  int*   tok_flat  = (int*)(ws + o);   o += PAD_SLOTS * 4;
  float* prob_flat = (float*)(ws + o); o += PAD_SLOTS * 4;
  int*   slot_of   = (int*)(ws + o);   o += T_TOK * 2 * 4;
  int*   eidx      = (int*)(ws + o);   o += T_TOK * 2 * 4;
  float* pval      = (float*)(ws + o); o += T_TOK * 2 * 4;
  int*   cnt       = (int*)(ws + o);   o += 32;
  int*   cursor    = (int*)(ws + o);   o += 32;
  int*   off       = (int*)(ws + o);   o += 64;

  hipMemsetAsync(cnt, 0, 32, stream);
  hipMemsetAsync(tok_flat, 0xFF, PAD_SLOTS * 4, stream);

  router_kernel<<<T_TOK, 64, 0, stream>>>(x, gate_w, eidx, pval, cnt);
  prefix_kernel<<<1, 64, 0, stream>>>(cnt, off, cursor);
  scatter_kernel<<<(T_TOK * 2) / 256, 256, 0, stream>>>(eidx, pval, cursor,
                                                        tok_flat, prob_flat, slot_of);
  xcast_kernel<<<(T_TOK * D_DIM) / (256 * 8), 256, 0, stream>>>(x, xb);

  // w1 [E][D][F] -> w1T [E][F][D]
  wtrans_kernel<<<dim3(F_DIM / 64, D_DIM / 64, E_EXP), 256, 0, stream>>>(w1, wT, D_DIM, F_DIM);
  gemm_kernel<0><<<E_EXP * 32 * (F_DIM / BN), 256, 0, stream>>>(
      xb, wT, b1, cnt, off, tok_flat, prob_flat, h, nullptr);

  // w2 [E][F][D] -> w2T [E][D][F]  (reuses wT buffer)
  wtrans_kernel<<<dim3(D_DIM / 64, F_DIM / 64, E_EXP), 256, 0, stream>>>(w2, wT, F_DIM, D_DIM);
  gemm_kernel<1><<<E_EXP * 32 * (D_DIM / BN), 256, 0, stream>>>(
      h, wT, b2, cnt, off, tok_flat, prob_flat, nullptr, y);

  combine_kernel<<<(T_TOK * D_DIM / 8) / 256, 256, 0, stream>>>(y, slot_of, out);
}